// Round 1
// 158.597 us; speedup vs baseline: 1.0181x; 1.0181x over previous
//
#include <hip/hip_runtime.h>
#include <math.h>

#define NEG_BIG  (-1e30f)
#define NEG_H16  (-60000.0f)   // "empty" marker safe in fp16

typedef _Float16 half8  __attribute__((ext_vector_type(8)));
typedef _Float16 half2v __attribute__((ext_vector_type(2)));
typedef float    floatx4 __attribute__((ext_vector_type(4)));

// ---------------------------------------------------------------------------
// Kernel 0 (fused aux), 513 blocks:
//   blocks 0..383 : feat fp32->fp16 (A-operand layout [c][p])
//   block  384    : per-LR-pixel folded constants
//       PA[p] = {-A2, -B2, -C2, -iC}        (rotation pre-expanded, pre-negated)
//       PB[p] = {2iC*G0, 2iC*G1, 2iC*G2, -iC*|G|^2}   (guide term expanded)
//       PS[p] = max(sx, sy)                 (for R bilinear upsample)
//   blocks 385..512: LC tables. 128 tables indexed (uc = Y>>4, bx = X0>>5);
//       each table [Pu][Pv][(R-1)*2+vcb] fp16 = ln(multiplicity). This was
//       previously rebuilt (divergent loops!) by every one of 2048 main blocks.
// ---------------------------------------------------------------------------
__global__ __launch_bounds__(256) void setup_all(
    const float* __restrict__ feat, const float* __restrict__ guide,
    const float* __restrict__ sx_raw, const float* __restrict__ sy_raw,
    const float* __restrict__ th_raw, const float* __restrict__ sr_raw,
    _Float16* __restrict__ feat16, float4* __restrict__ PA,
    float4* __restrict__ PB, float* __restrict__ PS,
    _Float16* __restrict__ LCtab)
{
    const int b = blockIdx.x, t = threadIdx.x;
    if (b < 384) {
        int i = b*256 + t;
        feat16[i] = (_Float16)feat[i];
        return;
    }
    if (b == 384) {
        float sx = expf(sx_raw[t]);
        float sy = expf(sy_raw[t]);
        float th = 3.14159265358979323846f * tanhf(th_raw[t]);
        float sr = expf(sr_raw[t]);
        float sxg = fmaxf(sx, 1e-6f), syg = fmaxf(sy, 1e-6f), srg = fmaxf(sr, 1e-6f);
        float iA = 1.f / (2.f*sxg*sxg + 1e-8f);
        float iB = 1.f / (2.f*syg*syg + 1e-8f);
        float iC = 1.f / (2.f*srg*srg + 1e-8f);
        float ct = cosf(th), st = sinf(th);
        float A2 = iA*ct*ct + iB*st*st;
        float B2 = 2.f*ct*st*(iA - iB);
        float C2 = iA*st*st + iB*ct*ct;
        PA[t] = make_float4(-A2, -B2, -C2, -iC);
        int i = t >> 4, j = t & 15;
        int y0 = 16*i + 7, x0 = 16*j + 7;   // bilinear 256->16 == 2x2 average
        float g[3];
#pragma unroll
        for (int c = 0; c < 3; ++c) {
            const float* gp = guide + c*65536;
            g[c] = 0.25f*(gp[y0*256 + x0]     + gp[y0*256 + x0 + 1] +
                          gp[(y0+1)*256 + x0] + gp[(y0+1)*256 + x0 + 1]);
        }
        PB[t] = make_float4(2.f*iC*g[0], 2.f*iC*g[1], 2.f*iC*g[2],
                            -iC*(g[0]*g[0] + g[1]*g[1] + g[2]*g[2]));
        PS[t] = fmaxf(sx, sy);
        return;
    }
    // ---- LC tables (identical math to the old in-kernel build) ----
    const int tb  = b - 385;          // 0..127
    const int uc  = tb >> 3;          // 0..15
    const int vc0 = (tb & 7) << 1;    // {0,2,...,14}  == X0>>4
    const int Pu  = t >> 4;
    const int col = t & 15;
    const int Rt  = (col >> 1) + 1;
    const int vc  = vc0 + (col & 1);
    const int R2  = Rt * Rt;
    int ylo = (Pu == 0)  ? -8 : (Pu - uc);
    int yhi = (Pu == 15) ?  8 : (Pu - uc);
    ylo = max(ylo, -8); yhi = min(yhi, 8);
    int cnt[16];
#pragma unroll
    for (int Pv = 1; Pv < 15; ++Pv) {
        int d = Pv - vc;
        int lim = R2 - d*d;
        int c = 0;
        if (lim >= 0 && ylo <= yhi) {
            int s = (int)sqrtf((float)lim);   // exact for ints <= 64
            c = max(0, min(yhi, s) - max(ylo, -s) + 1);
        }
        cnt[Pv] = c;
    }
    cnt[0] = 0;
    if (-vc >= -8) {
        for (int dY = ylo; dY <= yhi; ++dY) {
            int lim = R2 - dY*dY;
            if (lim >= 0) {
                int r = (int)sqrtf((float)lim);
                cnt[0] += max(0, min(-vc, r) + r + 1);
            }
        }
    }
    cnt[15] = 0;
    if (15 - vc <= 8) {
        for (int dY = ylo; dY <= yhi; ++dY) {
            int lim = R2 - dY*dY;
            if (lim >= 0) {
                int r = (int)sqrtf((float)lim);
                cnt[15] += max(0, r - max(15 - vc, -r) + 1);
            }
        }
    }
    _Float16* dst = LCtab + (size_t)tb * 4096;
#pragma unroll
    for (int Pv = 0; Pv < 16; ++Pv)
        dst[(Pu*16 + Pv)*16 + col] = (_Float16)
            ((cnt[Pv] > 0) ? __logf((float)cnt[Pv]) : NEG_H16);
}

// ---------------------------------------------------------------------------
// Kernel 1: main fused JBU. Same 1x32-strip / 256-thread structure as the
// verified baseline, with three changes:
//   (1) LCh is a staged COPY of the precomputed table (no divergent rebuild)
//   (2) phase-1 log-weight is a 7-FMA chain over folded PA/PB constants
//   (3) epilogue transposes through LDS (reusing LCh) -> dwordx4 stores
// LDS = 4+4+8+16+0.5+0.5 = 33 KB -> 4 blocks/CU.
// ---------------------------------------------------------------------------
__global__ __launch_bounds__(256, 4) void jbu_main(
    const float* __restrict__ guide, const _Float16* __restrict__ feat16,
    const float4* __restrict__ PA, const float4* __restrict__ PB,
    const float* __restrict__ PS, const _Float16* __restrict__ LCtab,
    float* __restrict__ out)
{
    __shared__ float4 sPA[256];                     // 4 KB
    __shared__ float4 sPB[256];                     // 4 KB
    __shared__ __align__(16) _Float16 LCh[4096];    // 8 KB; epilogue staging
    __shared__ __align__(16) _Float16 Wb[32][256];  // 16 KB, row=pixel, swizzled
    __shared__ float redM[4][32];                   // per-wave max partials
    __shared__ float redD[4][32];                   // per-wave den partials

    const int t = threadIdx.x;
    const int q    = t & 31;
    const int grp  = t >> 5;
    const int wv   = t >> 6;
    const int Y    = blockIdx.y;
    const int X0   = blockIdx.x << 5;
    const int X    = X0 + q;
    const float Yf = (float)Y, Xf = (float)X;
    const int uc   = Y >> 4;          // == clip(round(u),0,15) exactly

    // ---- Stage folded constants + this block's LC slice (all L2-hot) ----
    sPA[t] = PA[t];
    sPB[t] = PB[t];
    {
        const float4* Lsrc =
            (const float4*)(LCtab + (size_t)(uc*8 + blockIdx.x) * 4096);
        ((float4*)LCh)[t]       = Lsrc[t];
        ((float4*)LCh)[t + 256] = Lsrc[t + 256];
    }

    // ---- Per-pixel R from bilinear upsample of max(sx,sy) (PS, global) ----
    float u = (Yf + 0.5f)*0.0625f - 0.5f;
    float v = (Xf + 0.5f)*0.0625f - 0.5f;
    float ysc = fmaxf(u, 0.f), xsc = fmaxf(v, 0.f);
    int y0 = (int)ysc, x0 = (int)xsc;
    int y1 = min(y0 + 1, 15), x1 = min(x0 + 1, 15);
    float wy = ysc - (float)y0, wx = xsc - (float)x0;
    float s00 = PS[y0*16 + x0], s01 = PS[y0*16 + x1];
    float s10 = PS[y1*16 + x0], s11 = PS[y1*16 + x1];
    float sig = (1.f - wy)*((1.f - wx)*s00 + wx*s01)
              +        wy *((1.f - wx)*s10 + wx*s11);
    float Rf = fminf(fmaxf(ceilf(2.f*sig), 1.f), 8.f);
    const int colq = ((int)Rf - 1)*2 + (q >> 4);   // vcb = q>>4

    const float g0 = guide[          (Y << 8) + X];
    const float g1 = guide[ 65536 + ((Y << 8) + X)];
    const float g2 = guide[131072 + ((Y << 8) + X)];
    const float g2s = g0*g0 + g1*g1 + g2*g2;

    __syncthreads();   // B1: publishes sPA, sPB, LCh

    // ---- Phase 1: lw = ln(cnt) + folded 7-FMA chain, kept in registers ----
    const int pbase = grp << 5;
    const float dy0  = Yf - (32.f*(float)grp + 7.5f);
    const float dy1  = dy0 - 16.f;
    const float dy20 = dy0*dy0, dy21 = dy1*dy1;
    float lw[32];
    float mloc = NEG_BIG;
#pragma unroll
    for (int col = 0; col < 16; ++col) {
        float dx    = Xf - (16.f*(float)col + 7.5f);
        float dx2   = dx*dx;
        float dxdy0 = dx*dy0, dxdy1 = dx*dy1;
#pragma unroll
        for (int row = 0; row < 2; ++row) {
            int pi = row*16 + col;
            int p  = pbase + pi;
            float4 A = sPA[p];
            float4 B = sPB[p];
            float w = fmaf(B.x, g0, B.w);
            w = fmaf(B.y, g1, w);
            w = fmaf(B.z, g2, w);
            w = fmaf(A.w, g2s, w);
            w = fmaf(A.x, dx2, w);
            w = fmaf(A.y, row ? dxdy1 : dxdy0, w);
            w = fmaf(A.z, row ? dy21  : dy20,  w);
            w += (float)LCh[p*16 + colq];
            lw[pi] = w;
            mloc = fmaxf(mloc, w);
        }
    }
    mloc = fmaxf(mloc, __shfl_xor(mloc, 32, 64));  // combine wave's 2 p-groups
    redM[wv][q] = mloc;
    __syncthreads();   // B2
    float m = fmaxf(fmaxf(redM[0][q], redM[1][q]),
                    fmaxf(redM[2][q], redM[3][q]));

    // ---- Phase 2: exp, fp16 round, paired swizzled LDS stores, den ----
    float dloc = 0.f;
#pragma unroll
    for (int pi = 0; pi < 32; pi += 2) {
        int p = pbase + pi;
        float e0 = __expf(lw[pi]     - m);   // empty entries underflow to 0
        float e1 = __expf(lw[pi + 1] - m);
        half2v hh; hh[0] = (_Float16)e0; hh[1] = (_Float16)e1;
        int chunk = ((p >> 3) ^ q) & 31;     // 16B-chunk XOR swizzle
        *(half2v*)&Wb[q][chunk*8 + (p & 7)] = hh;
        dloc += (float)hh[0] + (float)hh[1]; // den consistent with fp16 weights
    }
    dloc += __shfl_xor(dloc, 32, 64);
    redD[wv][q] = dloc;
    __syncthreads();   // B3: publishes Wb + redD

    // ---- Phase 3: MFMA GEMM: out[c,pix] = invden * feat16 @ Wb ----
    const int lane = t & 63;
    const int mrow = lane & 15;
    const int quad = lane >> 4;
    const int c0   = wv * 96;

    float idv[2];
#pragma unroll
    for (int nt = 0; nt < 2; ++nt) {
        int pix = nt*16 + mrow;
        float den = redD[0][pix] + redD[1][pix] + redD[2][pix] + redD[3][pix];
        idv[nt] = 1.f / fmaxf(den, 1e-8f);
    }

    floatx4 acc[6][2] = {};
    const _Float16* fbase = feat16 + (c0 + mrow)*256 + quad*8;

#pragma unroll
    for (int ks = 0; ks < 8; ++ks) {
        half8 a[6];
#pragma unroll
        for (int mt = 0; mt < 6; ++mt)
            a[mt] = *(const half8*)(fbase + mt*16*256 + ks*32);
        half8 b[2];
#pragma unroll
        for (int nt = 0; nt < 2; ++nt) {
            int pix = nt*16 + mrow;
            int chunk = ((ks*4 + quad) ^ pix) & 31;
            b[nt] = *(const half8*)(&Wb[pix][chunk*8]);
        }
#pragma unroll
        for (int mt = 0; mt < 6; ++mt)
#pragma unroll
            for (int nt = 0; nt < 2; ++nt)
                acc[mt][nt] = __builtin_amdgcn_mfma_f32_16x16x32_f16(
                    a[mt], b[nt], acc[mt][nt], 0, 0, 0);
    }

    // ---- Epilogue: LDS transpose (per-wave 2 KB slice of dead LCh region)
    //      then full-line dwordx4 stores. LCh last read pre-B2; safe post-B3.
    float* Sf = (float*)LCh + (wv << 9);     // 512 floats per wave
    const int sch = lane >> 3;               // 0..7   channel sub-row
    const int spg = lane & 7;                // 0..7   pixel 4-group
    const int outcol = (Y << 8) + X0;
#pragma unroll
    for (int mt = 0; mt < 6; ++mt) {
#pragma unroll
        for (int nt = 0; nt < 2; ++nt)
#pragma unroll
            for (int r = 0; r < 4; ++r)
                Sf[(quad*4 + r)*32 + nt*16 + mrow] = acc[mt][nt][r] * idv[nt];
        // wave-synchronous RAW on same LDS alloc: compiler inserts lgkmcnt wait
#pragma unroll
        for (int j = 0; j < 2; ++j) {
            float4 vv = *(const float4*)&Sf[(j*8 + sch)*32 + spg*4];
            *(float4*)(out + (size_t)(c0 + mt*16 + j*8 + sch)*65536
                           + outcol + spg*4) = vv;
        }
    }
}

// ---------------------------------------------------------------------------
extern "C" void kernel_launch(void* const* d_in, const int* in_sizes, int n_in,
                              void* d_out, int out_size, void* d_ws, size_t ws_size,
                              hipStream_t stream)
{
    const float* feat   = (const float*)d_in[0];   // [1,384,16,16]
    const float* guide  = (const float*)d_in[1];   // [1,3,256,256]
    const float* sx_raw = (const float*)d_in[2];   // [1,1,16,16]
    const float* sy_raw = (const float*)d_in[3];
    const float* th_raw = (const float*)d_in[4];
    const float* sr_raw = (const float*)d_in[5];
    float* out = (float*)d_out;                    // [1,384,256,256]

    char* ws = (char*)d_ws;
    _Float16* feat16 = (_Float16*)ws;                    // 192 KB @ 0
    float4*   PA     = (float4*)(ws + 196608);           // 4 KB
    float4*   PB     = (float4*)(ws + 200704);           // 4 KB
    float*    PS     = (float*)(ws + 204800);            // 1 KB
    _Float16* LCtab  = (_Float16*)(ws + 205824);         // 1 MB (128 x 8 KB)

    setup_all<<<513, 256, 0, stream>>>(feat, guide, sx_raw, sy_raw, th_raw,
                                       sr_raw, feat16, PA, PB, PS, LCtab);
    jbu_main<<<dim3(8, 256), 256, 0, stream>>>(guide, feat16, PA, PB, PS,
                                               LCtab, out);
}